// Round 7
// baseline (374.239 us; speedup 1.0000x reference)
//
#include <hip/hip_runtime.h>

// IntensityTransformation: out_k[b,c,h,w] = tf_k[b,c, round(255*img[b,c,h,w])]
// B=8, C=3, H=W=1024, LUT=256. Memory-bound LUT gather (403 MB total traffic,
// HBM roofline ~64 us).
//
// v3: (a) all 8 img loads issued BEFORE any store, so s_waitcnt vmcnt(N) for a
// load never forces the store queue to drain (loads/stores share vmcnt on
// CDNA); (b) nontemporal stores for the 288 MiB of streaming output (no L2
// allocate); (c) 128 blocks/plane -> 3072 blocks, 12/CU.

#define PLANES 24                                   // B*C
#define PLANE_PIX (1024 * 1024)
#define VEC4_PER_PLANE (PLANE_PIX / 4)              // 262144
#define BLOCK 256
#define CHUNKS 128                                  // blocks per plane
#define ITERS (VEC4_PER_PLANE / (CHUNKS * BLOCK))   // 8 float4 per thread
#define TOTAL_VEC4 (PLANES * VEC4_PER_PLANE)        // 6291456

using f32x4 = __attribute__((ext_vector_type(4))) float;

// Gather + 3 nontemporal stores for one float4 of pixels at element idx.
// Macro so the LDS arrays keep addrspace(3) and we get ds_read_b32.
#define DO_PIX4(v, idx)                                                  \
    do {                                                                 \
        int i0 = __float2int_rn(255.0f * (v).x);                         \
        int i1 = __float2int_rn(255.0f * (v).y);                         \
        int i2 = __float2int_rn(255.0f * (v).z);                         \
        int i3 = __float2int_rn(255.0f * (v).w);                         \
        i0 = min(max(i0, 0), 255);                                       \
        i1 = min(max(i1, 0), 255);                                       \
        i2 = min(max(i2, 0), 255);                                       \
        i3 = min(max(i3, 0), 255);                                       \
        f32x4 o1 = {l1[i0], l1[i1], l1[i2], l1[i3]};                     \
        f32x4 o2 = {l2[i0], l2[i1], l2[i2], l2[i3]};                     \
        f32x4 o3 = {l3[i0], l3[i1], l3[i2], l3[i3]};                     \
        __builtin_nontemporal_store(o1, (f32x4*)&out[(idx)]);            \
        __builtin_nontemporal_store(o2, (f32x4*)&out[(idx) + TOTAL_VEC4]); \
        __builtin_nontemporal_store(o3,                                  \
            (f32x4*)&out[(idx) + 2 * TOTAL_VEC4]);                       \
    } while (0)

__global__ __launch_bounds__(BLOCK) void intensity_lut_kernel(
    const float4* __restrict__ img,
    const float*  __restrict__ tf1,
    const float*  __restrict__ tf2,
    const float*  __restrict__ tf3,
    float4* __restrict__ out)
{
    __shared__ float l1[256];
    __shared__ float l2[256];
    __shared__ float l3[256];

    const int plane = blockIdx.y;      // 0..23
    const int t = threadIdx.x;         // 0..255

    l1[t] = tf1[plane * 256 + t];
    l2[t] = tf2[plane * 256 + t];
    l3[t] = tf3[plane * 256 + t];
    __syncthreads();

    // Element indices fit in int32: max = 3*TOTAL_VEC4 = 18.9M (float4 units).
    const int base = plane * VEC4_PER_PLANE
                   + blockIdx.x * (BLOCK * ITERS) + t;

    const f32x4* imgv = (const f32x4*)img;

    // --- all loads first: no store ever precedes a pending load in vmcnt ---
    f32x4 v0 = imgv[base + 0 * BLOCK];
    f32x4 v1 = imgv[base + 1 * BLOCK];
    f32x4 v2 = imgv[base + 2 * BLOCK];
    f32x4 v3 = imgv[base + 3 * BLOCK];
    f32x4 v4 = imgv[base + 4 * BLOCK];
    f32x4 v5 = imgv[base + 5 * BLOCK];
    f32x4 v6 = imgv[base + 6 * BLOCK];
    f32x4 v7 = imgv[base + 7 * BLOCK];

    // --- gather + streaming stores, oldest load first ---
    DO_PIX4(v0, base + 0 * BLOCK);
    DO_PIX4(v1, base + 1 * BLOCK);
    DO_PIX4(v2, base + 2 * BLOCK);
    DO_PIX4(v3, base + 3 * BLOCK);
    DO_PIX4(v4, base + 4 * BLOCK);
    DO_PIX4(v5, base + 5 * BLOCK);
    DO_PIX4(v6, base + 6 * BLOCK);
    DO_PIX4(v7, base + 7 * BLOCK);
}

extern "C" void kernel_launch(void* const* d_in, const int* in_sizes, int n_in,
                              void* d_out, int out_size, void* d_ws, size_t ws_size,
                              hipStream_t stream) {
    const float4* img = (const float4*)d_in[0];
    const float*  tf1 = (const float*)d_in[1];
    const float*  tf2 = (const float*)d_in[2];
    const float*  tf3 = (const float*)d_in[3];
    float4* out = (float4*)d_out;

    dim3 grid(CHUNKS, PLANES);
    dim3 block(BLOCK);
    intensity_lut_kernel<<<grid, block, 0, stream>>>(img, tf1, tf2, tf3, out);
}